// Round 14
// baseline (608.324 us; speedup 1.0000x reference)
//
#include <hip/hip_runtime.h>
#include <math.h>

#ifndef M_PI
#define M_PI 3.14159265358979323846
#endif

#define NFILT   10
#define THREADS 1024
#define CHUNK   32                  // all register-resident
#define SEGLEN  (THREADS * CHUNK)   // 32768 = half a batch
#define LTOT    (SEGLEN * 2)        // 65536
#define NWAVE   (THREADS / 64)      // 16

#define WS_STRIDE 640               // floats per batch
#define MATS_OFF  96                // coefs j*8; matrices (j*10+r)*4 (r=0..9)
#define FLAG_OFF  576               // 10 ints  (filter-j ready flag)
#define STATE_OFF 592               // 10 float2 (filter-j end state of first half)

typedef float v2f __attribute__((ext_vector_type(2)));
__device__ inline v2f mk2(float a, float b) { v2f r; r.x = a; r.y = b; return r; }
#define F2(a,b,c) __builtin_elementwise_fma((a),(b),(c))

// ---------------- precompute (f64) ----------------

__device__ inline void biquad_coefs(int k, double w0r, double qir, double gr,
                                    double* bo, double* ao) {
    const double w0 = M_PI / (1.0 + exp(-w0r));
    const double qi = exp(qir);
    const double A  = exp(gr);
    const double cw = cos(w0);
    const double al = sin(w0) * qi * 0.5;
    double B0, B1, B2, A0, A1, A2;
    if (k == 0) {
        const double Ap1 = A + 1.0, Am1 = A - 1.0, tsa = 2.0 * sqrt(A) * al;
        B0 = A * (Ap1 - Am1 * cw + tsa);
        B1 = 2.0 * A * (Am1 - Ap1 * cw);
        B2 = A * (Ap1 - Am1 * cw - tsa);
        A0 = Ap1 + Am1 * cw + tsa;
        A1 = -2.0 * (Am1 + Ap1 * cw);
        A2 = Ap1 + Am1 * cw - tsa;
    } else if (k == NFILT - 1) {
        const double Ap1 = A + 1.0, Am1 = A - 1.0, tsa = 2.0 * sqrt(A) * al;
        B0 = A * (Ap1 + Am1 * cw + tsa);
        B1 = -2.0 * A * (Am1 + Ap1 * cw);
        B2 = A * (Ap1 + Am1 * cw - tsa);
        A0 = Ap1 - Am1 * cw + tsa;
        A1 = 2.0 * (Am1 - Ap1 * cw);
        A2 = Ap1 - Am1 * cw - tsa;
    } else {
        const double aA = al * A, aiA = al / A;
        B0 = 1.0 + aA;  B1 = -2.0 * cw; B2 = 1.0 - aA;
        A0 = 1.0 + aiA; A1 = B1;        A2 = 1.0 - aiA;
    }
    const double inv = 1.0 / A0;
    bo[0] = B0 * inv; bo[1] = B1 * inv; bo[2] = B2 * inv;
    ao[0] = 1.0;      ao[1] = A1 * inv; ao[2] = A2 * inv;
}

// coefs per filter j: [b0,b1,b2,a1,a2, qa1, qa2, 0]; matrices C^(32*2^r) r=0..9.
// Also zeroes the per-filter handoff flags/state (re-armed every launch).
__global__ void eq_precompute_kernel(const float* __restrict__ w0_in,
                                     const float* __restrict__ qinv_in,
                                     const float* __restrict__ gain_in,
                                     float* __restrict__ ws)
{
    const int b = blockIdx.x;
    const int j = threadIdx.x;
    if (j >= NFILT) return;

    double bo[3], ao[3];
    biquad_coefs(j, (double)w0_in[b*NFILT+j], (double)qinv_in[b*NFILT+j],
                 (double)gain_in[b*NFILT+j], bo, ao);

    float* wb = ws + (size_t)b * WS_STRIDE;
    float* cj = wb + j * 8;
    cj[0] = (float)bo[0]; cj[1] = (float)bo[1]; cj[2] = (float)bo[2];
    cj[3] = (float)ao[1]; cj[4] = (float)ao[2];
    cj[5] = (float)(ao[1]*ao[1] - ao[2]);   // qa1
    cj[6] = (float)(ao[1]*ao[2]);           // qa2

    double m0 = -ao[1], m1 = -ao[2], m2 = 1.0, m3 = 0.0;   // C
    #pragma unroll
    for (int i = 0; i < 5; ++i) {                          // -> C^32
        const double n0 = m0*m0 + m1*m2, n1 = m0*m1 + m1*m3;
        const double n2 = m2*m0 + m3*m2, n3 = m2*m1 + m3*m3;
        m0 = n0; m1 = n1; m2 = n2; m3 = n3;
    }
    for (int r = 0; r < 10; ++r) {                         // C^(32*2^r)
        float* mr = wb + MATS_OFF + (j*10 + r)*4;
        mr[0] = (float)m0; mr[1] = (float)m1; mr[2] = (float)m2; mr[3] = (float)m3;
        const double n0 = m0*m0 + m1*m2, n1 = m0*m1 + m1*m3;
        const double n2 = m2*m0 + m3*m2, n3 = m2*m1 + m3*m3;
        m0 = n0; m1 = n1; m2 = n2; m3 = n3;
    }
    ((int*)(wb + FLAG_OFF))[j] = 0;        // re-arm handoff
    wb[STATE_OFF + 2*j]     = 0.f;
    wb[STATE_OFF + 2*j + 1] = 0.f;
}

// ---------------- main kernel ----------------

__global__ void
__attribute__((amdgpu_flat_work_group_size(THREADS, THREADS)))
__attribute__((amdgpu_waves_per_eu(8, 8)))
eq_cascade_kernel(const float* __restrict__ x,
                  float* __restrict__ out,
                  float* __restrict__ ws)
{
    __shared__ float2 bnd[THREADS];
    __shared__ float2 waveP[2][NWAVE];
    __shared__ float2 incLDS;

    const int tid  = threadIdx.x;
    const int lane = tid & 63;
    const int wid  = tid >> 6;
    const int B    = gridDim.x >> 1;
    const int bid  = blockIdx.x;
    const int half = (bid >= B) ? 1 : 0;         // block0s (bids 0..B-1) dispatch first
    const int batch = half ? bid - B : bid;

    const float* __restrict__ wsb = ws + (size_t)batch * WS_STRIDE;
    int* flagp = (int*)(ws + (size_t)batch * WS_STRIDE + FLAG_OFF);
    volatile float* statep = ws + (size_t)batch * WS_STRIDE + STATE_OFF;

    const float* xb = x   + (size_t)batch * LTOT + (size_t)half * SEGLEN;
    float*       ob = out + (size_t)batch * LTOT + (size_t)half * SEGLEN;

    float sig[CHUNK];

    const float4* src = reinterpret_cast<const float4*>(xb + (size_t)tid * CHUNK);
    #pragma unroll
    for (int i = 0; i < CHUNK/4; ++i) {
        const float4 v = src[i];
        sig[4*i+0] = v.x; sig[4*i+1] = v.y; sig[4*i+2] = v.z; sig[4*i+3] = v.w;
    }
    bnd[tid] = make_float2(sig[CHUNK-1], sig[CHUNK-2]);
    __syncthreads();

    float xw1, xw2;     // raw-x history at this thread's chunk start
    if (tid == 0) {
        if (half) { xw1 = xb[-1]; xw2 = xb[-2]; }   // tail of first half (raw input)
        else      { xw1 = 0.f;    xw2 = 0.f;    }
    } else {
        const float2 t0 = bnd[tid - 1];
        xw1 = t0.x; xw2 = t0.y;
    }

    float i1 = 0.f, i2 = 0.f;
    v2f PA0p = mk2(0.f, 0.f), PA1p = mk2(0.f, 0.f), PA2p = mk2(0.f, 0.f);

    #pragma unroll 1
    for (int j = 0; j < NFILT; ++j) {
        const float* cj = wsb + j*8;
        const float b0 = cj[0], b1c = cj[1], b2 = cj[2];
        const float a1 = cj[3], a2 = cj[4], qa1 = cj[5], qa2 = cj[6];
        const v2f B0v = mk2(b0, b0), B1v = mk2(b1c, b1c), B2v = mk2(b2, b2);
        const v2f A0v = mk2(0.f, -a1), A1v = mk2(-a1, qa1), A2v = mk2(-a2, qa2);
        const float* mb = wsb + MATS_OFF + j*40;

        // ---- fused packed: finalize(j-1) + FIR(j) + zero-init(j) ----
        v2f Zp = mk2(0.f, 0.f);
        v2f Up;
        if (j == 0) {
            Up = mk2(xw2, xw1);
            #pragma unroll
            for (int i = 0; i < CHUNK/2; ++i) {
                const v2f U  = mk2(sig[2*i], sig[2*i+1]);
                const v2f M1 = mk2(Up.y, U.x);
                const v2f C  = F2(B2v, Up, F2(B1v, M1, B0v*U));
                const v2f Ch = F2(A0v, mk2(C.x, C.x), C);
                const v2f Z  = F2(A2v, mk2(Zp.x, Zp.x), F2(A1v, mk2(Zp.y, Zp.y), Ch));
                sig[2*i] = C.x; sig[2*i+1] = C.y;
                Up = U; Zp = Z;
            }
        } else {
            Up = mk2(i2, i1);
            #pragma unroll
            for (int i = 0; i < CHUNK/2; ++i) {
                const v2f S  = mk2(sig[2*i], sig[2*i+1]);
                const v2f Sh = F2(PA0p, mk2(S.x, S.x), S);
                const v2f U  = F2(PA2p, mk2(Up.x, Up.x), F2(PA1p, mk2(Up.y, Up.y), Sh));
                const v2f M1 = mk2(Up.y, U.x);
                const v2f C  = F2(B2v, Up, F2(B1v, M1, B0v*U));
                const v2f Ch = F2(A0v, mk2(C.x, C.x), C);
                const v2f Z  = F2(A2v, mk2(Zp.x, Zp.x), F2(A1v, mk2(Zp.y, Zp.y), Ch));
                sig[2*i] = C.x; sig[2*i+1] = C.y;
                Up = U; Zp = Z;
            }
        }

        // ---- in-wave inclusive affine scan of (z_new, z_prev) ----
        float Sa = Zp.y, Sb = Zp.x;
        #pragma unroll
        for (int r = 0; r < 6; ++r) {
            const int d = 1 << r;
            const float4 M = *reinterpret_cast<const float4*>(mb + r*4);
            float ta = __shfl_up(Sa, d, 64);
            float tb = __shfl_up(Sb, d, 64);
            const bool act = (lane >= d);
            ta = act ? ta : 0.f;
            tb = act ? tb : 0.f;
            Sa = Sa + M.x * ta + M.y * tb;
            Sb = Sb + M.z * ta + M.w * tb;
        }
        const int buf = j & 1;
        if (lane == 63) waveP[buf][wid] = make_float2(Sa, Sb);
        __syncthreads();

        // ---- cross-wave: 4-level KS over 16 wave totals (lane space) ----
        const float2 Pv = waveP[buf][lane & 15];
        float Tx = Pv.x, Ty = Pv.y;
        #pragma unroll
        for (int l = 0; l < 4; ++l) {
            const int d = 1 << l;
            const float4 M = *reinterpret_cast<const float4*>(mb + (6+l)*4);
            float tx = __shfl_up(Tx, d, 64);
            float ty = __shfl_up(Ty, d, 64);
            const bool act = (lane >= d);
            tx = act ? tx : 0.f;
            ty = act ? ty : 0.f;
            Tx = Tx + M.x * tx + M.y * ty;
            Ty = Ty + M.z * tx + M.w * ty;
        }

        // ---- handoff: first half publishes; second half consumes ----
        if (!half) {
            if (tid == 15) {          // lane 15 of wave 0 holds the 16-wave total
                statep[2*j]   = Tx;
                statep[2*j+1] = Ty;
                __threadfence();
                atomicExch(&flagp[j], 1);
            }
        } else {
            if (tid == 0) {
                while (atomicAdd(&flagp[j], 0) == 0) { }
                __threadfence();
                incLDS = make_float2(statep[2*j], statep[2*j+1]);
            }
            __syncthreads();
        }

        // wave-incoming particular state
        float Vx = __shfl(Tx, wid - 1, 64);
        float Vy = __shfl(Ty, wid - 1, 64);
        if (wid == 0) { Vx = 0.f; Vy = 0.f; }
        if (half) {                   // + C^(2048*wid) * inc
            float hx = incLDS.x, hy = incLDS.y;
            #pragma unroll
            for (int l = 0; l < 4; ++l) {
                const float4 M = *reinterpret_cast<const float4*>(mb + (6+l)*4);
                const bool bit = (wid >> l) & 1;
                const float nx = M.x * hx + M.y * hy;
                const float ny = M.z * hx + M.w * hy;
                hx = bit ? nx : hx;
                hy = bit ? ny : hy;
            }
            Vx += hx; Vy += hy;
        }
        #pragma unroll
        for (int r = 0; r < 6; ++r) {      // apply C^(32*lane)
            const float4 M = *reinterpret_cast<const float4*>(mb + r*4);
            const bool bit = (lane >> r) & 1;
            const float nx = M.x * Vx + M.y * Vy;
            const float ny = M.z * Vx + M.w * Vy;
            Vx = bit ? nx : Vx;
            Vy = bit ? ny : Vy;
        }
        {
            float Ea = __shfl_up(Sa, 1, 64);
            float Eb = __shfl_up(Sb, 1, 64);
            const bool l0 = (lane == 0);
            i1 = Vx + (l0 ? 0.f : Ea);
            i2 = Vy + (l0 ? 0.f : Eb);
        }
        PA0p = A0v; PA1p = A1v; PA2p = A2v;
    }

    // ---- tail: packed finalize of filter 9 + store ----
    {
        v2f Up = mk2(i2, i1);
        float4* dst = reinterpret_cast<float4*>(ob + (size_t)tid * CHUNK);
        #pragma unroll
        for (int i = 0; i < CHUNK/4; ++i) {
            float4 o;
            #pragma unroll
            for (int h = 0; h < 2; ++h) {
                const v2f S  = (h == 0) ? mk2(sig[4*i], sig[4*i+1]) : mk2(sig[4*i+2], sig[4*i+3]);
                const v2f Sh = F2(PA0p, mk2(S.x, S.x), S);
                const v2f U  = F2(PA2p, mk2(Up.x, Up.x), F2(PA1p, mk2(Up.y, Up.y), Sh));
                if (h == 0) { o.x = U.x; o.y = U.y; } else { o.z = U.x; o.w = U.y; }
                Up = U;
            }
            dst[i] = o;
        }
    }
}

extern "C" void kernel_launch(void* const* d_in, const int* in_sizes, int n_in,
                              void* d_out, int out_size, void* d_ws, size_t ws_size,
                              hipStream_t stream) {
    const float* x    = (const float*)d_in[0];
    const float* w0   = (const float*)d_in[1];
    const float* qinv = (const float*)d_in[2];
    const float* gain = (const float*)d_in[3];
    float* out = (float*)d_out;
    float* ws  = (float*)d_ws;   // 256 * 640 * 4 B = 640 KiB

    const int B = in_sizes[1] / NFILT;   // 256 batches
    eq_precompute_kernel<<<B, 64, 0, stream>>>(w0, qinv, gain, ws);
    eq_cascade_kernel<<<2 * B, THREADS, 0, stream>>>(x, out, ws);
}

// Round 15
// 79.119 us; speedup vs baseline: 7.6887x; 7.6887x over previous
//
#include <hip/hip_runtime.h>
#include <math.h>

#ifndef M_PI
#define M_PI 3.14159265358979323846
#endif

#define NFILT   10
#define THREADS 1024
#define CHUNK   64                  // 32 samples in VGPRs + 32 in LDS
#define REGS    32
#define LDSS    (CHUNK - REGS)
#define LTOT    (THREADS * CHUNK)   // 65536
#define NWAVE   (THREADS / 64)      // 16

#define WS_STRIDE 576               // floats per batch
#define MATS_OFF  96                // coefs: j*8; matrices: (j*10+r)*4 (r=0..6 used)

typedef float v2f __attribute__((ext_vector_type(2)));
__device__ inline v2f mk2(float a, float b) { v2f r; r.x = a; r.y = b; return r; }
#define F2(a,b,c) __builtin_elementwise_fma((a),(b),(c))

// ---------------- precompute (f64) ----------------

__device__ inline void biquad_coefs(int k, double w0r, double qir, double gr,
                                    double* bo, double* ao) {
    const double w0 = M_PI / (1.0 + exp(-w0r));
    const double qi = exp(qir);
    const double A  = exp(gr);
    const double cw = cos(w0);
    const double al = sin(w0) * qi * 0.5;
    double B0, B1, B2, A0, A1, A2;
    if (k == 0) {
        const double Ap1 = A + 1.0, Am1 = A - 1.0, tsa = 2.0 * sqrt(A) * al;
        B0 = A * (Ap1 - Am1 * cw + tsa);
        B1 = 2.0 * A * (Am1 - Ap1 * cw);
        B2 = A * (Ap1 - Am1 * cw - tsa);
        A0 = Ap1 + Am1 * cw + tsa;
        A1 = -2.0 * (Am1 + Ap1 * cw);
        A2 = Ap1 + Am1 * cw - tsa;
    } else if (k == NFILT - 1) {
        const double Ap1 = A + 1.0, Am1 = A - 1.0, tsa = 2.0 * sqrt(A) * al;
        B0 = A * (Ap1 + Am1 * cw + tsa);
        B1 = -2.0 * A * (Am1 + Ap1 * cw);
        B2 = A * (Ap1 + Am1 * cw - tsa);
        A0 = Ap1 - Am1 * cw + tsa;
        A1 = 2.0 * (Am1 - Ap1 * cw);
        A2 = Ap1 - Am1 * cw - tsa;
    } else {
        const double aA = al * A, aiA = al / A;
        B0 = 1.0 + aA;  B1 = -2.0 * cw; B2 = 1.0 - aA;
        A0 = 1.0 + aiA; A1 = B1;        A2 = 1.0 - aiA;
    }
    const double inv = 1.0 / A0;
    bo[0] = B0 * inv; bo[1] = B1 * inv; bo[2] = B2 * inv;
    ao[0] = 1.0;      ao[1] = A1 * inv; ao[2] = A2 * inv;
}

// coefs per filter j: [b0,b1,b2,a1,a2, qa1=a1^2-a2, qa2=a1*a2, 0]
// matrices: C^(64*2^r), r=0..9 (r<=6 used), row-major (m0,m1,m2,m3)
__global__ void eq_precompute_kernel(const float* __restrict__ w0_in,
                                     const float* __restrict__ qinv_in,
                                     const float* __restrict__ gain_in,
                                     float* __restrict__ ws)
{
    const int b = blockIdx.x;
    const int j = threadIdx.x;
    if (j >= NFILT) return;

    double bo[3], ao[3];
    biquad_coefs(j, (double)w0_in[b*NFILT+j], (double)qinv_in[b*NFILT+j],
                 (double)gain_in[b*NFILT+j], bo, ao);

    float* wb = ws + (size_t)b * WS_STRIDE;
    float* cj = wb + j * 8;
    cj[0] = (float)bo[0]; cj[1] = (float)bo[1]; cj[2] = (float)bo[2];
    cj[3] = (float)ao[1]; cj[4] = (float)ao[2];
    cj[5] = (float)(ao[1]*ao[1] - ao[2]);   // qa1
    cj[6] = (float)(ao[1]*ao[2]);           // qa2

    double m0 = -ao[1], m1 = -ao[2], m2 = 1.0, m3 = 0.0;   // C
    #pragma unroll
    for (int i = 0; i < 6; ++i) {                          // -> C^64
        const double n0 = m0*m0 + m1*m2, n1 = m0*m1 + m1*m3;
        const double n2 = m2*m0 + m3*m2, n3 = m2*m1 + m3*m3;
        m0 = n0; m1 = n1; m2 = n2; m3 = n3;
    }
    for (int r = 0; r < 10; ++r) {                         // C^(64*2^r)
        float* mr = wb + MATS_OFF + (j*10 + r)*4;
        mr[0] = (float)m0; mr[1] = (float)m1; mr[2] = (float)m2; mr[3] = (float)m3;
        const double n0 = m0*m0 + m1*m2, n1 = m0*m1 + m1*m3;
        const double n2 = m2*m0 + m3*m2, n3 = m2*m1 + m3*m3;
        m0 = n0; m1 = n1; m2 = n2; m3 = n3;
    }
}

// ---------------- main kernel ----------------

__global__ void
__attribute__((amdgpu_flat_work_group_size(THREADS, THREADS)))
__attribute__((amdgpu_waves_per_eu(4, 4)))
eq_cascade_kernel(const float* __restrict__ x,
                  float* __restrict__ out,
                  const float* __restrict__ ws)
{
    __shared__ float4 sigh[LDSS/4][THREADS];     // samples 32..63 (thread-private)
    __shared__ float2 bnd[THREADS];
    __shared__ float2 waveT[NFILT][NWAVE];       // inclusive wave totals, write-once
    volatile __shared__ int wflag[NWAVE];        // # filters published per wave

    const int tid  = threadIdx.x;
    const int lane = tid & 63;
    const int wid  = tid >> 6;
    const int b    = blockIdx.x;
    const float* __restrict__ wsb = ws + (size_t)b * WS_STRIDE;

    const float* xb = x   + (size_t)b * LTOT;
    float*       ob = out + (size_t)b * LTOT;

    float sig[REGS];

    // ---- load 64 samples: first 32 -> regs, last 32 -> LDS ----
    const float4* src = reinterpret_cast<const float4*>(xb + (size_t)tid * CHUNK);
    #pragma unroll
    for (int i = 0; i < REGS/4; ++i) {
        const float4 v = src[i];
        sig[4*i+0] = v.x; sig[4*i+1] = v.y; sig[4*i+2] = v.z; sig[4*i+3] = v.w;
    }
    float4 vlast;
    #pragma unroll
    for (int i = 0; i < LDSS/4; ++i) {
        const float4 v = src[REGS/4 + i];
        sigh[i][tid] = v;
        if (i == LDSS/4 - 1) vlast = v;
    }
    bnd[tid] = make_float2(vlast.w, vlast.z);
    if (tid < NWAVE) wflag[tid] = 0;
    __syncthreads();                 // the ONLY barrier

    float xw1, xw2;
    {
        const float2 t0 = (tid == 0) ? make_float2(0.f, 0.f) : bnd[tid - 1];
        xw1 = t0.x; xw2 = t0.y;
    }
    float i1 = 0.f, i2 = 0.f;
    v2f PA0p = mk2(0.f, 0.f), PA1p = mk2(0.f, 0.f), PA2p = mk2(0.f, 0.f);

    #pragma unroll 1
    for (int j = 0; j < NFILT; ++j) {
        const float* cj = wsb + j*8;
        const float b0 = cj[0], b1c = cj[1], b2 = cj[2];
        const float a1 = cj[3], a2 = cj[4], qa1 = cj[5], qa2 = cj[6];
        const v2f B0v = mk2(b0, b0), B1v = mk2(b1c, b1c), B2v = mk2(b2, b2);
        const v2f A0v = mk2(0.f, -a1), A1v = mk2(-a1, qa1), A2v = mk2(-a2, qa2);
        const float* mb = wsb + MATS_OFF + j*40;

        // ---- fused packed: finalize(j-1) + FIR(j) + zero-init(j), pair-stepped ----
        v2f Zp = mk2(0.f, 0.f);
        v2f Up;
        if (j == 0) {
            Up = mk2(xw2, xw1);
            #pragma unroll
            for (int i = 0; i < REGS/2; ++i) {
                const v2f U  = mk2(sig[2*i], sig[2*i+1]);
                const v2f M1 = mk2(Up.y, U.x);
                const v2f C  = F2(B2v, Up, F2(B1v, M1, B0v*U));
                const v2f Ch = F2(A0v, mk2(C.x, C.x), C);
                const v2f Z  = F2(A2v, mk2(Zp.x, Zp.x), F2(A1v, mk2(Zp.y, Zp.y), Ch));
                sig[2*i] = C.x; sig[2*i+1] = C.y;
                Up = U; Zp = Z;
            }
            #pragma unroll
            for (int i = 0; i < LDSS/4; ++i) {
                const float4 v = sigh[i][tid];
                float4 r;
                #pragma unroll
                for (int h = 0; h < 2; ++h) {
                    const v2f U  = (h == 0) ? mk2(v.x, v.y) : mk2(v.z, v.w);
                    const v2f M1 = mk2(Up.y, U.x);
                    const v2f C  = F2(B2v, Up, F2(B1v, M1, B0v*U));
                    const v2f Ch = F2(A0v, mk2(C.x, C.x), C);
                    const v2f Z  = F2(A2v, mk2(Zp.x, Zp.x), F2(A1v, mk2(Zp.y, Zp.y), Ch));
                    if (h == 0) { r.x = C.x; r.y = C.y; } else { r.z = C.x; r.w = C.y; }
                    Up = U; Zp = Z;
                }
                sigh[i][tid] = r;
            }
        } else {
            Up = mk2(i2, i1);
            #pragma unroll
            for (int i = 0; i < REGS/2; ++i) {
                const v2f S  = mk2(sig[2*i], sig[2*i+1]);
                const v2f Sh = F2(PA0p, mk2(S.x, S.x), S);
                const v2f U  = F2(PA2p, mk2(Up.x, Up.x), F2(PA1p, mk2(Up.y, Up.y), Sh));
                const v2f M1 = mk2(Up.y, U.x);
                const v2f C  = F2(B2v, Up, F2(B1v, M1, B0v*U));
                const v2f Ch = F2(A0v, mk2(C.x, C.x), C);
                const v2f Z  = F2(A2v, mk2(Zp.x, Zp.x), F2(A1v, mk2(Zp.y, Zp.y), Ch));
                sig[2*i] = C.x; sig[2*i+1] = C.y;
                Up = U; Zp = Z;
            }
            #pragma unroll
            for (int i = 0; i < LDSS/4; ++i) {
                const float4 v = sigh[i][tid];
                float4 r;
                #pragma unroll
                for (int h = 0; h < 2; ++h) {
                    const v2f S  = (h == 0) ? mk2(v.x, v.y) : mk2(v.z, v.w);
                    const v2f Sh = F2(PA0p, mk2(S.x, S.x), S);
                    const v2f U  = F2(PA2p, mk2(Up.x, Up.x), F2(PA1p, mk2(Up.y, Up.y), Sh));
                    const v2f M1 = mk2(Up.y, U.x);
                    const v2f C  = F2(B2v, Up, F2(B1v, M1, B0v*U));
                    const v2f Ch = F2(A0v, mk2(C.x, C.x), C);
                    const v2f Z  = F2(A2v, mk2(Zp.x, Zp.x), F2(A1v, mk2(Zp.y, Zp.y), Ch));
                    if (h == 0) { r.x = C.x; r.y = C.y; } else { r.z = C.x; r.w = C.y; }
                    Up = U; Zp = Z;
                }
                sigh[i][tid] = r;
            }
        }

        // ---- in-wave inclusive affine scan of (z_newest, z_second) ----
        float Sa = Zp.y, Sb = Zp.x;
        #pragma unroll
        for (int r = 0; r < 6; ++r) {
            const int d = 1 << r;
            const float4 M = *reinterpret_cast<const float4*>(mb + r*4);
            float ta = __shfl_up(Sa, d, 64);
            float tb = __shfl_up(Sb, d, 64);
            const bool act = (lane >= d);
            ta = act ? ta : 0.f;
            tb = act ? tb : 0.f;
            Sa = Sa + M.x * ta + M.y * tb;
            Sb = Sb + M.z * ta + M.w * tb;
        }

        // ---- decoupled lookback across waves (no barrier) ----
        float Tpx = 0.f, Tpy = 0.f;           // T_{w-1} (inclusive over waves < wid)
        if (wid > 0) {
            while (wflag[wid - 1] < j + 1) { }
            __threadfence_block();
            volatile const float* wtp = (volatile const float*)&waveT[j][wid - 1];
            Tpx = wtp[0]; Tpy = wtp[1];
        }
        if (lane == 63) {                      // publish inclusive total T_w
            const float4 M6 = *reinterpret_cast<const float4*>(mb + 6*4);
            const float Twx = Sa + M6.x * Tpx + M6.y * Tpy;
            const float Twy = Sb + M6.z * Tpx + M6.w * Tpy;
            waveT[j][wid] = make_float2(Twx, Twy);
            __threadfence_block();
            wflag[wid] = j + 1;
        }

        // wave-incoming state V = T_{w-1}; apply C^(64*lane); + exclusive prefix
        float Vx = Tpx, Vy = Tpy;
        #pragma unroll
        for (int r = 0; r < 6; ++r) {
            const float4 M = *reinterpret_cast<const float4*>(mb + r*4);
            const bool bit = (lane >> r) & 1;
            const float nx = M.x * Vx + M.y * Vy;
            const float ny = M.z * Vx + M.w * Vy;
            Vx = bit ? nx : Vx;
            Vy = bit ? ny : Vy;
        }
        {
            float Ea = __shfl_up(Sa, 1, 64);
            float Eb = __shfl_up(Sb, 1, 64);
            const bool l0 = (lane == 0);
            i1 = Vx + (l0 ? 0.f : Ea);
            i2 = Vy + (l0 ? 0.f : Eb);
        }
        PA0p = A0v; PA1p = A1v; PA2p = A2v;
    }

    // ---- tail: packed finalize of filter 9 + store ----
    {
        v2f Up = mk2(i2, i1);
        float4* dst = reinterpret_cast<float4*>(ob + (size_t)tid * CHUNK);
        #pragma unroll
        for (int i = 0; i < REGS/4; ++i) {
            float4 o;
            #pragma unroll
            for (int h = 0; h < 2; ++h) {
                const v2f S  = (h == 0) ? mk2(sig[4*i], sig[4*i+1]) : mk2(sig[4*i+2], sig[4*i+3]);
                const v2f Sh = F2(PA0p, mk2(S.x, S.x), S);
                const v2f U  = F2(PA2p, mk2(Up.x, Up.x), F2(PA1p, mk2(Up.y, Up.y), Sh));
                if (h == 0) { o.x = U.x; o.y = U.y; } else { o.z = U.x; o.w = U.y; }
                Up = U;
            }
            dst[i] = o;
        }
        #pragma unroll
        for (int i = 0; i < LDSS/4; ++i) {
            const float4 v = sigh[i][tid];
            float4 o;
            #pragma unroll
            for (int h = 0; h < 2; ++h) {
                const v2f S  = (h == 0) ? mk2(v.x, v.y) : mk2(v.z, v.w);
                const v2f Sh = F2(PA0p, mk2(S.x, S.x), S);
                const v2f U  = F2(PA2p, mk2(Up.x, Up.x), F2(PA1p, mk2(Up.y, Up.y), Sh));
                if (h == 0) { o.x = U.x; o.y = U.y; } else { o.z = U.x; o.w = U.y; }
                Up = U;
            }
            dst[REGS/4 + i] = o;
        }
    }
}

extern "C" void kernel_launch(void* const* d_in, const int* in_sizes, int n_in,
                              void* d_out, int out_size, void* d_ws, size_t ws_size,
                              hipStream_t stream) {
    const float* x    = (const float*)d_in[0];
    const float* w0   = (const float*)d_in[1];
    const float* qinv = (const float*)d_in[2];
    const float* gain = (const float*)d_in[3];
    float* out = (float*)d_out;
    float* ws  = (float*)d_ws;   // 256 * 576 * 4 B = 576 KiB

    const int B = in_sizes[1] / NFILT;   // 256 batches
    eq_precompute_kernel<<<B, 64, 0, stream>>>(w0, qinv, gain, ws);
    eq_cascade_kernel<<<B, THREADS, 0, stream>>>(x, out, ws);
}